// Round 3
// baseline (71.502 us; speedup 1.0000x reference)
//
#include <hip/hip_runtime.h>
#include <stdint.h>

// Problem constants (from reference)
#define BB 32
#define NN 16384
#define RR 24
#define IMS 64
#define NPIX (IMS * IMS)                  // 4096
#define RPB 3                              // rotations per block
#define GROUPS (RR / RPB)                  // 8 rotation groups
#define SCRATCH (RPB * 64)                 // per-lane OOB slots (bank-uniform)
#define LDSN (RPB * NPIX + SCRATCH)

// One block per (b, rotation-group-of-3); grid = 256 = one per CU. Each
// block reads its batch's 16384 points once and scatters each point into 3
// rotation images held in LDS (~48.75 KB + scratch).
//
// LDS images hold u32 packed keys: ((n+1)<<17) | (float_bits(zr)>>15).
// n+1 <= 2^14 in the top 15 bits -> atomicMax == numpy last-write-wins
// (pixel choice bit-exact). Low 17 bits carry sign+exp+8 mantissa of zr;
// truncation ~2e-3 after /10 vs threshold 9.77e-3.
//
// R2 (this round):
//  1. COALESCED LOADS. Old scheme (6 float4/thread) gave each wave-load a
//     96-byte lane stride -> 64 distinct cache lines PER INSTRUCTION (384
//     line-requests per wave-iter) -- TA-serialized. Now instr j has lane l
//     load point (w*1024 + j*64 + l) at 12-byte stride: 768 contiguous
//     bytes/wave = 12 lines per instruction. Point->thread assignment is
//     semantics-free (n rides in the key).
//  2. WORKING bank decorrelator. R1's (px^py) XORed two variables whose
//     mod-32 mass both concentrate near {0,31}; XOR stays concentrated ->
//     swizzle was a no-op. Now slot = py*64 + ((px + 37*py) & 63):
//     bijective per row, 37*py mod 64 sweeps all residues across py's
//     +-1 sigma range -> near-uniform banks (~2 lanes/bank = free). py=0
//     row unswizzled -> pixel (0,0) is still word 0 (OOB merge target).
//  3. Keep R0/R1: unconditional atomics, OOB -> per-lane scratch slot
//     (bank = lane%32), tiny max-merge epilogue into pixel (0,0).
__global__ __launch_bounds__(1024) void rotproj_lds(
    const float* __restrict__ xyz, const float* __restrict__ rot,
    float* __restrict__ out) {
  __shared__ unsigned int img[LDSN];

  const int blk = blockIdx.x;        // 0..255
  const int b = blk >> 3;            // / GROUPS
  const int rg = blk & (GROUPS - 1); // rotation group; r = rg*3 + rl

  for (int i = threadIdx.x; i < LDSN; i += 1024) img[i] = 0u;

  const float* m = rot + rg * RPB * 9;
  float c0[RPB], c2[RPB], c6[RPB], c8[RPB];
#pragma unroll
  for (int rl = 0; rl < RPB; ++rl) {
    c0[rl] = m[rl * 9 + 0];
    c2[rl] = m[rl * 9 + 2];
    c6[rl] = m[rl * 9 + 6];
    c8[rl] = m[rl * 9 + 8];
  }

  const int w = threadIdx.x >> 6;    // wave id 0..15
  const int lane = threadIdx.x & 63;
  int srel[RPB];  // scratch word index relative to rl*NPIX (per-rl constant)
#pragma unroll
  for (int rl = 0; rl < RPB; ++rl)
    srel[rl] = (RPB - rl) * NPIX + rl * 64 + lane;  // rl*NPIX + srel = scratch

  __syncthreads();

  const float* pts = xyz + (size_t)b * NN * 3;

  // 2 outer iters x 8 points. Point n = w*1024 + iter*512 + jj*64 + lane:
  // per load instruction the wave reads 768 contiguous bytes (12 lines).
#pragma unroll
  for (int iter = 0; iter < 2; ++iter) {
    const int nbase = w * 1024 + iter * 512 + lane;
    float X[8], Y[8], Z[8];
#pragma unroll
    for (int jj = 0; jj < 8; ++jj) {
      const float* p = pts + 3 * (nbase + jj * 64);
      X[jj] = p[0];
      Y[jj] = p[1];
      Z[jj] = p[2];
    }

#pragma unroll
    for (int jj = 0; jj < 8; ++jj) {
      const float x = X[jj], y = Y[jj], z = Z[jj];
      const int n = nbase + jj * 64;

      // py is rotation-independent: yr == y bitwise for rotations about y.
      // (v+2)*16 == fma(v,16,32) exactly; rintf = RNE = np.round.
      const int py = (int)rintf(__fmaf_rn(y, 16.0f, 32.0f));
      const bool pyin = (unsigned)py < (unsigned)IMS;
      const int pybase = py * IMS;
      const int s = 37 * py;                    // row-dependent slot shift
      const unsigned int nkey = (unsigned)(n + 1) << 17;

#pragma unroll
      for (int rl = 0; rl < RPB; ++rl) {
        // xr chooses the pixel: bit-exact vs np.einsum
        // ((m0*x + 0*y) + m2*z), no FMA fusion.
        const float xr =
            __fadd_rn(__fmul_rn(c0[rl], x), __fmul_rn(c2[rl], z));
        // zr is value-only (low key bits; winner picked by n in top bits):
        // FMA is safe.
        const float zr = __fmaf_rn(c6[rl], x, __fmul_rn(c8[rl], z));

        const int px = (int)rintf(__fmaf_rn(xr, 16.0f, 32.0f));
        const bool in = ((unsigned)px < (unsigned)IMS) & pyin;

        const unsigned int key = nkey | (__float_as_uint(zr) >> 15);

        // Swizzled in-range slot ((px+s)&63 <= 63 -> always a valid word
        // even for wild px; discarded via cndmask when OOB). OOB -> this
        // lane's scratch slot. Unconditional atomic, no exec churn.
        const int slot = pybase + ((px + s) & 63);
        const int word = in ? slot : srel[rl];
        atomicMax(&img[rl * NPIX + word], key);
      }
    }
  }

  __syncthreads();

  // Merge OOB scratch into pixel (0,0) of each image (word rl*NPIX; py=0
  // row is unswizzled). 3 wave-ops; max-n semantics == direct OOB writes.
  if (threadIdx.x < SCRATCH) {
    const unsigned int k = img[RPB * NPIX + threadIdx.x];
    if (k) atomicMax(&img[(threadIdx.x >> 6) * NPIX], k);
  }

  __syncthreads();

  // Resolve: the 3 rotation images are contiguous in out (r = rg*3 + rl).
  // Pixel (py,px) lives at word py*64 + ((px + 37*py)&63); per wave py is
  // constant -> the read is a pure lane permutation (conflict-free) and
  // the global write stays coalesced.
  float* oslice = out + ((size_t)b * RR + (size_t)rg * RPB) * NPIX;
#pragma unroll
  for (int t = 0; t < RPB * NPIX / 1024; ++t) {
    const int i = t * 1024 + threadIdx.x;
    const int py = (i >> 6) & (IMS - 1);
    const int px = i & (IMS - 1);
    const unsigned int k = img[(i & ~(IMS - 1)) | ((px + 37 * py) & 63)];
    const float zr = __uint_as_float((k & 0x1FFFFu) << 15);
    oslice[i] = k ? (zr / 10.0f) : 0.0f;
  }
}

extern "C" void kernel_launch(void* const* d_in, const int* in_sizes, int n_in,
                              void* d_out, int out_size, void* d_ws,
                              size_t ws_size, hipStream_t stream) {
  const float* xyz = (const float*)d_in[0];
  const float* rot = (const float*)d_in[1];
  float* out = (float*)d_out;

  rotproj_lds<<<BB * GROUPS, 1024, 0, stream>>>(xyz, rot, out);
}

// Round 4
// 70.182 us; speedup vs baseline: 1.0188x; 1.0188x over previous
//
#include <hip/hip_runtime.h>
#include <stdint.h>

// Problem constants (from reference)
#define BB 32
#define NN 16384
#define RR 24
#define IMS 64
#define NPIX (IMS * IMS)                  // 4096
#define RPB 3                              // rotations per block
#define GROUPS (RR / RPB)                  // 8 rotation groups
#define SCRATCH (RPB * 64)                 // per-lane OOB slots (bank-uniform)
#define LDSN (RPB * NPIX + SCRATCH)

// One block per (b, rotation-group-of-3); grid = 256 = one per CU. Each
// block reads its batch's 16384 points once and scatters each point into 3
// rotation images held in LDS (~48.75 KB + scratch).
//
// LDS images hold u32 packed keys: ((n+1)<<17) | (float_bits(zr)>>15).
// n+1 <= 2^14 in the top 15 bits -> atomic max == numpy last-write-wins
// (pixel choice bit-exact). Low 17 bits carry sign+exp+8 mantissa of zr;
// truncation ~2e-3 after /10 vs threshold 9.77e-3.
//
// Round history (kernel portion = headline - ~40.5us harness poison fill):
//  R0: unconditional atomics (no exec churn)      -> neutral (VALU not limit)
//  R1: OOB->scratch dispersal, (broken) xor swz   -> neutral
//  R2: coalesced 12B-stride loads, working swizzle-> neutral (banks/loads
//      not limit)
// Surviving theory: DS-atomic pipe is lane-count-bound at ~1.4 cy/lane;
// 49152 lane-RMWs/CU (algorithm-invariant) ~= 29us = observed.
//
// R3 (this round): test the last per-op overhead candidate -- atomic
// LOWERING. Default atomicMax is agent-scope; __hip_atomic_fetch_max with
// RELAXED + WORKGROUP scope and unused result guarantees bare ds_max_u32
// (no return, no fences, no CAS loop). If neutral, the DS-lane-rate floor
// stands. Also: resolve epilogue vectorized to float4 stores (12 -> 3
// iterations; 4x swizzled ds_read_b32 per thread stay <=2-way bank-uniform:
// groups of 16 lanes cover each row once, row-to-row shift 37 keeps banks
// disjoint across the 4 row-groups of a wave).
__global__ __launch_bounds__(1024) void rotproj_lds(
    const float* __restrict__ xyz, const float* __restrict__ rot,
    float* __restrict__ out) {
  __shared__ unsigned int img[LDSN];

  const int blk = blockIdx.x;        // 0..255
  const int b = blk >> 3;            // / GROUPS
  const int rg = blk & (GROUPS - 1); // rotation group; r = rg*3 + rl

  for (int i = threadIdx.x; i < LDSN; i += 1024) img[i] = 0u;

  const float* m = rot + rg * RPB * 9;
  float c0[RPB], c2[RPB], c6[RPB], c8[RPB];
#pragma unroll
  for (int rl = 0; rl < RPB; ++rl) {
    c0[rl] = m[rl * 9 + 0];
    c2[rl] = m[rl * 9 + 2];
    c6[rl] = m[rl * 9 + 6];
    c8[rl] = m[rl * 9 + 8];
  }

  const int w = threadIdx.x >> 6;    // wave id 0..15
  const int lane = threadIdx.x & 63;
  int srel[RPB];  // scratch word index relative to rl*NPIX (per-rl constant)
#pragma unroll
  for (int rl = 0; rl < RPB; ++rl)
    srel[rl] = (RPB - rl) * NPIX + rl * 64 + lane;  // rl*NPIX + srel = scratch

  __syncthreads();

  const float* pts = xyz + (size_t)b * NN * 3;

  // 2 outer iters x 8 points. Point n = w*1024 + iter*512 + jj*64 + lane:
  // per load instruction the wave reads 768 contiguous bytes (12 lines).
#pragma unroll
  for (int iter = 0; iter < 2; ++iter) {
    const int nbase = w * 1024 + iter * 512 + lane;
    float X[8], Y[8], Z[8];
#pragma unroll
    for (int jj = 0; jj < 8; ++jj) {
      const float* p = pts + 3 * (nbase + jj * 64);
      X[jj] = p[0];
      Y[jj] = p[1];
      Z[jj] = p[2];
    }

#pragma unroll
    for (int jj = 0; jj < 8; ++jj) {
      const float x = X[jj], y = Y[jj], z = Z[jj];
      const int n = nbase + jj * 64;

      // py is rotation-independent: yr == y bitwise for rotations about y.
      // (v+2)*16 == fma(v,16,32) exactly; rintf = RNE = np.round.
      const int py = (int)rintf(__fmaf_rn(y, 16.0f, 32.0f));
      const bool pyin = (unsigned)py < (unsigned)IMS;
      const int pybase = py * IMS;
      const int s = 37 * py;                    // row-dependent slot shift
      const unsigned int nkey = (unsigned)(n + 1) << 17;

#pragma unroll
      for (int rl = 0; rl < RPB; ++rl) {
        // xr chooses the pixel: bit-exact vs np.einsum
        // ((m0*x + 0*y) + m2*z), no FMA fusion.
        const float xr =
            __fadd_rn(__fmul_rn(c0[rl], x), __fmul_rn(c2[rl], z));
        // zr is value-only (low key bits; winner picked by n in top bits):
        // FMA is safe.
        const float zr = __fmaf_rn(c6[rl], x, __fmul_rn(c8[rl], z));

        const int px = (int)rintf(__fmaf_rn(xr, 16.0f, 32.0f));
        const bool in = ((unsigned)px < (unsigned)IMS) & pyin;

        const unsigned int key = nkey | (__float_as_uint(zr) >> 15);

        // Swizzled in-range slot; OOB -> this lane's scratch slot.
        // Unconditional atomic, no exec churn. RELAXED + WORKGROUP scope +
        // unused result -> bare ds_max_u32 (no rtn, no fences, no CAS).
        const int slot = pybase + ((px + s) & 63);
        const int word = in ? slot : srel[rl];
        (void)__hip_atomic_fetch_max(&img[rl * NPIX + word], key,
                                     __ATOMIC_RELAXED,
                                     __HIP_MEMORY_SCOPE_WORKGROUP);
      }
    }
  }

  __syncthreads();

  // Merge OOB scratch into pixel (0,0) of each image (word rl*NPIX; py=0
  // row is unswizzled). 3 wave-ops; max-n semantics == direct OOB writes.
  if (threadIdx.x < SCRATCH) {
    const unsigned int k = img[RPB * NPIX + threadIdx.x];
    if (k)
      (void)__hip_atomic_fetch_max(&img[(threadIdx.x >> 6) * NPIX], k,
                                   __ATOMIC_RELAXED,
                                   __HIP_MEMORY_SCOPE_WORKGROUP);
  }

  __syncthreads();

  // Resolve: the 3 rotation images are contiguous in out (r = rg*3 + rl).
  // Pixel (py,px) lives at word py*64 + ((px + 37*py)&63). Each thread
  // handles 4 consecutive px of one row (quads never cross rows) -> one
  // float4 store (wave: 1KB contiguous). The 4 ds_read_b32 are <=2-way
  // bank-uniform: 16-lane groups cover a row once; 37-shift between the
  // wave's 4 rows keeps their bank sets disjoint.
  float* oslice = out + ((size_t)b * RR + (size_t)rg * RPB) * NPIX;
#pragma unroll
  for (int t = 0; t < RPB * NPIX / 4096; ++t) {
    const int i = (t * 1024 + threadIdx.x) * 4;   // first pixel of the quad
    const int py = (i >> 6) & (IMS - 1);
    const int rowbase = i & ~(IMS - 1);           // includes rl*NPIX
    const int s = 37 * py;
    float4 o;
    float* po = &o.x;
#pragma unroll
    for (int q = 0; q < 4; ++q) {
      const int px = (i + q) & (IMS - 1);
      const unsigned int k = img[rowbase | ((px + s) & (IMS - 1))];
      const float zr = __uint_as_float((k & 0x1FFFFu) << 15);
      po[q] = k ? (zr / 10.0f) : 0.0f;
    }
    *(float4*)(&oslice[i]) = o;
  }
}

extern "C" void kernel_launch(void* const* d_in, const int* in_sizes, int n_in,
                              void* d_out, int out_size, void* d_ws,
                              size_t ws_size, hipStream_t stream) {
  const float* xyz = (const float*)d_in[0];
  const float* rot = (const float*)d_in[1];
  float* out = (float*)d_out;

  rotproj_lds<<<BB * GROUPS, 1024, 0, stream>>>(xyz, rot, out);
}